// Round 15
// baseline (357.964 us; speedup 1.0000x reference)
//
#include <hip/hip_runtime.h>

#define EMBED 512
#define EXPAND 1024
#define PNUM 16
#define NLEN 1024
#define CHW (PNUM * NLEN)  // 16384
#define SLABS 64

typedef unsigned short u16;
typedef unsigned int u32;
typedef __bf16 bf16x8 __attribute__((ext_vector_type(8)));
typedef u16 u16x8 __attribute__((ext_vector_type(8)));
typedef float f32x4 __attribute__((ext_vector_type(4)));

__device__ __forceinline__ u16 f2bf(float f) {
  u32 u = __builtin_bit_cast(u32, f);
  return (u16)((u + 0x7FFFu + ((u >> 16) & 1u)) >> 16);
}
__device__ __forceinline__ float bf2f(u16 h) {
  return __builtin_bit_cast(float, (u32)h << 16);
}
__device__ __forceinline__ void gld16(const u16* g, u16* l) {
  __builtin_amdgcn_global_load_lds((__attribute__((address_space(1))) void*)g,
                                   (__attribute__((address_space(3))) void*)l,
                                   16, 0, 0);
}
__device__ __forceinline__ f32x4 MFMA(bf16x8 a, bf16x8 b, f32x4 c) {
  return __builtin_amdgcn_mfma_f32_16x16x32_bf16(a, b, c, 0, 0, 0);
}

// ---------------- Kernel W: weights fp32 -> bf16 ----------------
__global__ __launch_bounds__(256) void k_convert_w(
    const float* __restrict__ Wqkv, const float* __restrict__ Wout,
    u16* __restrict__ WvB, u16* __restrict__ WoutB) {
  const int NV = EXPAND * EMBED;  // 524288
  int idx = (blockIdx.x * 256 + threadIdx.x) * 4;
  if (idx < NV) {
    float4 v = *(const float4*)(Wqkv + (size_t)(1 + EXPAND) * EMBED + idx);
    uint2 u = make_uint2((u32)f2bf(v.x) | ((u32)f2bf(v.y) << 16),
                         (u32)f2bf(v.z) | ((u32)f2bf(v.w) << 16));
    *(uint2*)(WvB + idx) = u;
  } else {
    int j = idx - NV;
    float4 v = *(const float4*)(Wout + j);
    uint2 u = make_uint2((u32)f2bf(v.x) | ((u32)f2bf(v.y) << 16),
                         (u32)f2bf(v.z) | ((u32)f2bf(v.w) << 16));
    *(uint2*)(WoutB + j) = u;
  }
}

// ---------------- Kernel A: x -> bf16 transposed + query GEMV partials ------
__global__ __launch_bounds__(256) void k_convert_x(
    const float* __restrict__ x, const float* __restrict__ Wqkv,
    float* __restrict__ qpart, u16* __restrict__ xbT) {
  __shared__ __align__(16) u16 tile[128 * 64];  // 16 KB
  __shared__ float qp[256 * 4];                 // 4 KB
  const int slab = blockIdx.x >> 4;
  const int nw = (blockIdx.x >> 1) & 7;
  const int chalf = blockIdx.x & 1;
  const int b = slab >> 4, p = slab & 15;
  const int t = threadIdx.x;
  const int c8 = t & 7;
  const int ng = t >> 3;
  const float* xs = x + (size_t)b * (EMBED * CHW) + (size_t)p * NLEN + nw * 128;
  u16* dst = xbT + (size_t)slab * (NLEN * EMBED) + (size_t)(nw * 128) * EMBED;
  float qa[4] = {0.f, 0.f, 0.f, 0.f};

  for (int cc = 0; cc < 4; ++cc) {
    const int cbase = chalf * 256 + cc * 64;
    float4 v[8];
#pragma unroll
    for (int k = 0; k < 8; ++k)
      v[k] = *(const float4*)(xs + (size_t)(cbase + c8 * 8 + k) * CHW + ng * 4);
    const float* w0 = Wqkv + cbase + c8 * 8;
#pragma unroll
    for (int k = 0; k < 8; ++k) {
      qa[0] += w0[k] * v[k].x;
      qa[1] += w0[k] * v[k].y;
      qa[2] += w0[k] * v[k].z;
      qa[3] += w0[k] * v[k].w;
    }
#pragma unroll
    for (int j = 0; j < 4; ++j) {
      const int nl = ng * 4 + j;
      float e[8];
#pragma unroll
      for (int k = 0; k < 8; ++k)
        e[k] = (j == 0) ? v[k].x : (j == 1) ? v[k].y : (j == 2) ? v[k].z : v[k].w;
      uint4 pk;
      pk.x = (u32)f2bf(e[0]) | ((u32)f2bf(e[1]) << 16);
      pk.y = (u32)f2bf(e[2]) | ((u32)f2bf(e[3]) << 16);
      pk.z = (u32)f2bf(e[4]) | ((u32)f2bf(e[5]) << 16);
      pk.w = (u32)f2bf(e[6]) | ((u32)f2bf(e[7]) << 16);
      *(uint4*)(tile + nl * 64 + ((c8 ^ (nl & 7)) << 3)) = pk;
    }
    __syncthreads();
#pragma unroll
    for (int m = 0; m < 4; ++m) {
      const int s = m * 256 + t;
      const int nl = s >> 3, ch = s & 7;
      uint4 vv = *(const uint4*)(tile + nl * 64 + ((ch ^ (nl & 7)) << 3));
      *(uint4*)(dst + (size_t)nl * EMBED + cbase + ch * 8) = vv;
    }
    __syncthreads();
  }
  qp[t * 4 + 0] = qa[0];
  qp[t * 4 + 1] = qa[1];
  qp[t * 4 + 2] = qa[2];
  qp[t * 4 + 3] = qa[3];
  __syncthreads();
  if (t < 128) {
    float a = 0.f;
#pragma unroll
    for (int o = 0; o < 8; ++o) a += qp[((((t >> 2) << 3) + o) << 2) + (t & 3)];
    qpart[(size_t)slab * 2048 + chalf * 1024 + nw * 128 + t] = a;
  }
}

// ---------------- attn1: softmax + partial y over an n-eighth ---------------
__global__ __launch_bounds__(256) void k_attn1(
    const float* __restrict__ qpart, const u16* __restrict__ xbT,
    float* __restrict__ ypart) {
  __shared__ float red[4];
  __shared__ float sm[128];
  __shared__ float yp[4][512];
  const int slab = blockIdx.x >> 3, n8 = blockIdx.x & 7;
  const int t = threadIdx.x, w = t >> 6, l = t & 63;
  const float* q0 = qpart + (size_t)slab * 2048;
  const float* q1 = q0 + 1024;

  float4 qa = ((const float4*)q0)[t];
  float4 qb = ((const float4*)q1)[t];
  float4 q4 = make_float4(qa.x + qb.x, qa.y + qb.y, qa.z + qb.z, qa.w + qb.w);
  float m = fmaxf(fmaxf(q4.x, q4.y), fmaxf(q4.z, q4.w));
#pragma unroll
  for (int sh = 32; sh; sh >>= 1) m = fmaxf(m, __shfl_xor(m, sh, 64));
  if (l == 0) red[w] = m;
  __syncthreads();
  float gm = fmaxf(fmaxf(red[0], red[1]), fmaxf(red[2], red[3]));
  float s = __expf(q4.x - gm) + __expf(q4.y - gm) + __expf(q4.z - gm) + __expf(q4.w - gm);
#pragma unroll
  for (int sh = 32; sh; sh >>= 1) s += __shfl_xor(s, sh, 64);
  __syncthreads();
  if (l == 0) red[w] = s;
  __syncthreads();
  float gs = red[0] + red[1] + red[2] + red[3];
  if (t < 128) {
    const int n = n8 * 128 + t;
    sm[t] = __expf(q0[n] + q1[n] - gm) / gs;
  }
  __syncthreads();

  float ya[8] = {0.f, 0.f, 0.f, 0.f, 0.f, 0.f, 0.f, 0.f};
  const u16* xs = xbT + (size_t)slab * (NLEN * EMBED) + (size_t)(n8 * 128) * EMBED;
  for (int ni = 0; ni < 32; ++ni) {
    const int nloc = ni * 4 + w;
    const float sc = sm[nloc];
    u16x8 v = *(const u16x8*)(xs + (size_t)nloc * EMBED + l * 8);
#pragma unroll
    for (int j = 0; j < 8; ++j) ya[j] += sc * bf2f(v[j]);
  }
#pragma unroll
  for (int j = 0; j < 8; ++j) yp[w][l * 8 + j] = ya[j];
  __syncthreads();
  for (int c = t; c < 512; c += 256)
    ypart[((size_t)slab * 8 + n8) * 512 + c] = yp[0][c] + yp[1][c] + yp[2][c] + yp[3][c];
}

// ---------------- attn2: cv[e] = Wk[e]·y + bk[e] ----------------------------
__global__ __launch_bounds__(256) void k_attn2(
    const float* __restrict__ ypart, const float* __restrict__ Wqkv,
    const float* __restrict__ bqkv, float* __restrict__ cv) {
  __shared__ float yl[512];
  const int slab = blockIdx.x >> 2, ec = blockIdx.x & 3;
  const int t = threadIdx.x;
  const int e = ec * 256 + t;
  const float* yb = ypart + (size_t)slab * 8 * 512;
  for (int c = t; c < 512; c += 256) {
    float a = 0.f;
#pragma unroll
    for (int k = 0; k < 8; ++k) a += yb[k * 512 + c];
    yl[c] = a;
  }
  __syncthreads();
  const float* wk = Wqkv + (size_t)(1 + e) * EMBED;
  float a = 0.f;
#pragma unroll 4
  for (int c0 = 0; c0 < EMBED; c0 += 4) {
    float4 wv = *(const float4*)(wk + c0);
    a += wv.x * yl[c0] + wv.y * yl[c0 + 1] + wv.z * yl[c0 + 2] + wv.w * yl[c0 + 3];
  }
  cv[(size_t)slab * EXPAND + e] = a + bqkv[1 + e];
}

// ---------------- 128x128 GEMM core (m97 structure, BK=64, 32 KB LDS) -------
// D[128(m),128(n)] = A(128,K)*B(128,K)^T, k-contiguous rows, stride K.
// 256 thr = 4 waves (2m x 2n); per wave 64x64 out = acc[4][4].
// LDS 32 KB single-buffered (A 16K | B 16K), 16B-chunk swizzle ch^(row&7).
// Plain 2-barrier loop: stage -> sync -> 16 ds_read_b128 + 32 MFMA -> sync.
// Win mechanism = cross-block overlap (m114): VGPR 60 + 32 KB LDS caps at
// 5 blocks/CU; __launch_bounds__(256,5) lets dispatch actually pack them.
template <int K, int NT>
__device__ __forceinline__ void gemm128(const u16* __restrict__ Abase,
                                        const u16* __restrict__ Bbase,
                                        u16* lds, f32x4 (&acc)[4][4]) {
  const int t = threadIdx.x;
  const int w = t >> 6, l = t & 63;
  const int wr = w >> 1, wc = w & 1;
  const int lr = l & 15, lj = l >> 4;

#pragma unroll 1
  for (int kt = 0; kt < NT; ++kt) {
    const int kc0 = kt * 64;
#pragma unroll
    for (int i = 0; i < 4; ++i) {
      const int s = i * 256 + t;
      const int row = s >> 3, pch = s & 7;
      const int gch = (pch ^ (row & 7)) << 3;
      gld16(Abase + (size_t)row * K + kc0 + gch, lds + s * 8);
      gld16(Bbase + (size_t)row * K + kc0 + gch, lds + 8192 + s * 8);
    }
    __syncthreads();  // drains vmcnt -> staged data visible
    bf16x8 af[4][2], bg[4][2];
#pragma unroll
    for (int mi = 0; mi < 4; ++mi)
#pragma unroll
      for (int kc = 0; kc < 2; ++kc) {
        const int row = wr * 64 + mi * 16 + lr;
        af[mi][kc] = *(const bf16x8*)(lds + row * 64 +
                                      (((kc * 4 + lj) ^ (row & 7)) << 3));
      }
#pragma unroll
    for (int ni = 0; ni < 4; ++ni)
#pragma unroll
      for (int kc = 0; kc < 2; ++kc) {
        const int row = wc * 64 + ni * 16 + lr;
        bg[ni][kc] = *(const bf16x8*)(lds + 8192 + row * 64 +
                                      (((kc * 4 + lj) ^ (row & 7)) << 3));
      }
#pragma unroll
    for (int mi = 0; mi < 4; ++mi)
#pragma unroll
      for (int ni = 0; ni < 4; ++ni)
#pragma unroll
        for (int kc = 0; kc < 2; ++kc)
          acc[mi][ni] = MFMA(af[mi][kc], bg[ni][kc], acc[mi][ni]);
    __syncthreads();  // buffer reusable next iteration
  }
}

// ---------------- GEMM1: midT[n][e] = relu(valT + bv)*cv, bf16 --------------
// grid 4096 = 64 slabs x 8 tn x 8 te; te-siblings at bid stride 8 (same XCD).
__global__ __launch_bounds__(256, 5) void k_gemm1(
    const u16* __restrict__ xbT, const u16* __restrict__ WvB,
    const float* __restrict__ bqkv, const float* __restrict__ cv,
    u16* __restrict__ midT) {
  __shared__ __align__(16) u16 lds[16384];  // 32 KB
  const int bid = blockIdx.x;
  const int xc = bid & 7, k = bid >> 3;
  const int te = k & 7;
  const int gg = ((k >> 3) << 3) | xc;  // 0..511
  const int slab = gg >> 3, tn = gg & 7;
  const u16* A = xbT + (size_t)slab * (NLEN * EMBED) + (size_t)tn * 128 * EMBED;
  const u16* B = WvB + (size_t)te * 128 * EMBED;
  f32x4 acc[4][4];
  const f32x4 z = {0.f, 0.f, 0.f, 0.f};
#pragma unroll
  for (int i = 0; i < 4; ++i)
#pragma unroll
    for (int j = 0; j < 4; ++j) acc[i][j] = z;
  gemm128<EMBED, 8>(A, B, lds, acc);
  // loop tail: final __syncthreads -> LDS reusable for the C-tile (32 KB).

  const int t = threadIdx.x, w = t >> 6, l = t & 63;
  const int wr = w >> 1, wc = w & 1;
  const int lr = l & 15, lq4 = (l >> 4) * 4;
  // C tile 128n x 128e bf16 into LDS, chunk swizzle ch^(row&7) (16 chunks/row)
#pragma unroll
  for (int ni = 0; ni < 4; ++ni) {
    const int col = wc * 64 + ni * 16 + lr;
    const int e = te * 128 + col;
    const float bv = bqkv[1 + EXPAND + e];
    const float cve = cv[(size_t)slab * EXPAND + e];
#pragma unroll
    for (int mi = 0; mi < 4; ++mi) {
      const int nr = wr * 64 + mi * 16 + lq4;
#pragma unroll
      for (int r = 0; r < 4; ++r) {
        float v = acc[mi][ni][r] + bv;
        v = v > 0.f ? v * cve : 0.f;
        const int row = nr + r;
        lds[row * 128 + ((((col >> 3) ^ (row & 7)) << 3) | (col & 7))] = f2bf(v);
      }
    }
  }
  __syncthreads();
  // wide stores: wave w owns rows w*32..w*32+31; 4 rows x 16 chunks per iter
  u16* mt = midT + (size_t)slab * (NLEN * EXPAND) + (size_t)te * 128;
#pragma unroll
  for (int it = 0; it < 8; ++it) {
    const int row = w * 32 + it * 4 + (l >> 4);
    const int ch = (l & 15) ^ (row & 7);
    uint4 v = *(const uint4*)(lds + row * 128 + ch * 8);
    *(uint4*)(mt + (size_t)(tn * 128 + row) * EXPAND + (l & 15) * 8) = v;
  }
}

// ---------------- GEMM2: out = Wout*mid + bout ------------------------------
// grid 2048 = 64 slabs x 8 tn x 4 to; to-siblings at bid stride 8 (same XCD).
__global__ __launch_bounds__(256, 5) void k_gemm2(
    const u16* __restrict__ midT, const u16* __restrict__ WoutB,
    const float* __restrict__ bout, float* __restrict__ out) {
  __shared__ __align__(16) u16 lds[16384];  // 32 KB
  const int bid = blockIdx.x;
  const int xc = bid & 7, k = bid >> 3;
  const int to = k & 3;
  const int gg = ((k >> 2) << 3) | xc;  // 0..511
  const int slab = gg >> 3, tn = gg & 7;
  const int b = slab >> 4, p = slab & 15;
  const u16* A = midT + (size_t)slab * (NLEN * EXPAND) + (size_t)tn * 128 * EXPAND;
  const u16* B = WoutB + (size_t)to * 128 * EXPAND;
  f32x4 acc[4][4];
  const f32x4 z = {0.f, 0.f, 0.f, 0.f};
#pragma unroll
  for (int i = 0; i < 4; ++i)
#pragma unroll
    for (int j = 0; j < 4; ++j) acc[i][j] = z;
  gemm128<EXPAND, 16>(A, B, lds, acc);

  const int t = threadIdx.x, w = t >> 6, l = t & 63;
  const int wr = w >> 1, wc = w & 1;
  const int lr = l & 15, lq4 = (l >> 4) * 4;
  float* ob = out + (size_t)b * (EMBED * CHW) + (size_t)p * NLEN;
#pragma unroll
  for (int ni = 0; ni < 4; ++ni) {
    const int o = to * 128 + wc * 64 + ni * 16 + lr;
    const float bo = bout[o];
#pragma unroll
    for (int mi = 0; mi < 4; ++mi) {
      const int nr = tn * 128 + wr * 64 + mi * 16 + lq4;
      float4 v;
      v.x = acc[mi][ni][0] + bo;
      v.y = acc[mi][ni][1] + bo;
      v.z = acc[mi][ni][2] + bo;
      v.w = acc[mi][ni][3] + bo;
      *(float4*)(ob + (size_t)o * CHW + nr) = v;
    }
  }
}

extern "C" void kernel_launch(void* const* d_in, const int* in_sizes, int n_in,
                              void* d_out, int out_size, void* d_ws, size_t ws_size,
                              hipStream_t stream) {
  const float* x = (const float*)d_in[0];
  const float* Wqkv = (const float*)d_in[1];
  const float* bqkv = (const float*)d_in[2];
  const float* Wout = (const float*)d_in[3];
  const float* bout = (const float*)d_in[4];
  float* out = (float*)d_out;

  char* ws = (char*)d_ws;
  u16* xbT = (u16*)ws;                  // 67108864 B
  u16* WvB = (u16*)(ws + 67108864);     // 1048576 B
  u16* WoutB = (u16*)(ws + 68157440);   // 1048576 B
  float* cv = (float*)(ws + 69468160);  // 262144 B
  u16* midT = (u16*)(ws + 69730304);    // 134217728 B
  // overlays on midT's head (all consumed before gemm1 writes midT):
  float* ypart = (float*)(ws + 69730304);             // 64*8*512*4 = 1 MB
  float* qpart = (float*)(ws + 69730304 + 1048576);   // 64*2*1024*4 = 512 KB

  k_convert_w<<<1024, 256, 0, stream>>>(Wqkv, Wout, WvB, WoutB);
  k_convert_x<<<1024, 256, 0, stream>>>(x, Wqkv, qpart, xbT);
  k_attn1<<<512, 256, 0, stream>>>(qpart, xbT, ypart);
  k_attn2<<<256, 256, 0, stream>>>(ypart, Wqkv, bqkv, cv);
  k_gemm1<<<4096, 256, 0, stream>>>(xbT, WvB, bqkv, cv, midT);
  k_gemm2<<<2048, 256, 0, stream>>>(midT, WoutB, bout, out);
}

// Round 16
// 260.616 us; speedup vs baseline: 1.3735x; 1.3735x over previous
//
#include <hip/hip_runtime.h>

#define EMBED 512
#define EXPAND 1024
#define PNUM 16
#define NLEN 1024
#define CHW (PNUM * NLEN)  // 16384
#define SLABS 64

typedef unsigned short u16;
typedef unsigned int u32;
typedef __bf16 bf16x8 __attribute__((ext_vector_type(8)));
typedef u16 u16x8 __attribute__((ext_vector_type(8)));
typedef float f32x4 __attribute__((ext_vector_type(4)));

__device__ __forceinline__ u16 f2bf(float f) {
  u32 u = __builtin_bit_cast(u32, f);
  return (u16)((u + 0x7FFFu + ((u >> 16) & 1u)) >> 16);
}
__device__ __forceinline__ float bf2f(u16 h) {
  return __builtin_bit_cast(float, (u32)h << 16);
}
__device__ __forceinline__ void gld16(const u16* g, u16* l) {
  __builtin_amdgcn_global_load_lds((__attribute__((address_space(1))) void*)g,
                                   (__attribute__((address_space(3))) void*)l,
                                   16, 0, 0);
}
__device__ __forceinline__ f32x4 MFMA(bf16x8 a, bf16x8 b, f32x4 c) {
  return __builtin_amdgcn_mfma_f32_16x16x32_bf16(a, b, c, 0, 0, 0);
}

// ---------------- Kernel W: weights fp32 -> bf16 ----------------
__global__ __launch_bounds__(256) void k_convert_w(
    const float* __restrict__ Wqkv, const float* __restrict__ Wout,
    u16* __restrict__ WvB, u16* __restrict__ WoutB) {
  const int NV = EXPAND * EMBED;  // 524288
  int idx = (blockIdx.x * 256 + threadIdx.x) * 4;
  if (idx < NV) {
    float4 v = *(const float4*)(Wqkv + (size_t)(1 + EXPAND) * EMBED + idx);
    uint2 u = make_uint2((u32)f2bf(v.x) | ((u32)f2bf(v.y) << 16),
                         (u32)f2bf(v.z) | ((u32)f2bf(v.w) << 16));
    *(uint2*)(WvB + idx) = u;
  } else {
    int j = idx - NV;
    float4 v = *(const float4*)(Wout + j);
    uint2 u = make_uint2((u32)f2bf(v.x) | ((u32)f2bf(v.y) << 16),
                         (u32)f2bf(v.z) | ((u32)f2bf(v.w) << 16));
    *(uint2*)(WoutB + j) = u;
  }
}

// ---------------- Kernel A: x -> bf16 transposed + query GEMV partials ------
__global__ __launch_bounds__(256) void k_convert_x(
    const float* __restrict__ x, const float* __restrict__ Wqkv,
    float* __restrict__ qpart, u16* __restrict__ xbT) {
  __shared__ __align__(16) u16 tile[128 * 64];  // 16 KB
  __shared__ float qp[256 * 4];                 // 4 KB
  const int slab = blockIdx.x >> 4;
  const int nw = (blockIdx.x >> 1) & 7;
  const int chalf = blockIdx.x & 1;
  const int b = slab >> 4, p = slab & 15;
  const int t = threadIdx.x;
  const int c8 = t & 7;
  const int ng = t >> 3;
  const float* xs = x + (size_t)b * (EMBED * CHW) + (size_t)p * NLEN + nw * 128;
  u16* dst = xbT + (size_t)slab * (NLEN * EMBED) + (size_t)(nw * 128) * EMBED;
  float qa[4] = {0.f, 0.f, 0.f, 0.f};

  for (int cc = 0; cc < 4; ++cc) {
    const int cbase = chalf * 256 + cc * 64;
    float4 v[8];
#pragma unroll
    for (int k = 0; k < 8; ++k)
      v[k] = *(const float4*)(xs + (size_t)(cbase + c8 * 8 + k) * CHW + ng * 4);
    const float* w0 = Wqkv + cbase + c8 * 8;
#pragma unroll
    for (int k = 0; k < 8; ++k) {
      qa[0] += w0[k] * v[k].x;
      qa[1] += w0[k] * v[k].y;
      qa[2] += w0[k] * v[k].z;
      qa[3] += w0[k] * v[k].w;
    }
#pragma unroll
    for (int j = 0; j < 4; ++j) {
      const int nl = ng * 4 + j;
      float e[8];
#pragma unroll
      for (int k = 0; k < 8; ++k)
        e[k] = (j == 0) ? v[k].x : (j == 1) ? v[k].y : (j == 2) ? v[k].z : v[k].w;
      uint4 pk;
      pk.x = (u32)f2bf(e[0]) | ((u32)f2bf(e[1]) << 16);
      pk.y = (u32)f2bf(e[2]) | ((u32)f2bf(e[3]) << 16);
      pk.z = (u32)f2bf(e[4]) | ((u32)f2bf(e[5]) << 16);
      pk.w = (u32)f2bf(e[6]) | ((u32)f2bf(e[7]) << 16);
      *(uint4*)(tile + nl * 64 + ((c8 ^ (nl & 7)) << 3)) = pk;
    }
    __syncthreads();
#pragma unroll
    for (int m = 0; m < 4; ++m) {
      const int s = m * 256 + t;
      const int nl = s >> 3, ch = s & 7;
      uint4 vv = *(const uint4*)(tile + nl * 64 + ((ch ^ (nl & 7)) << 3));
      *(uint4*)(dst + (size_t)nl * EMBED + cbase + ch * 8) = vv;
    }
    __syncthreads();
  }
  qp[t * 4 + 0] = qa[0];
  qp[t * 4 + 1] = qa[1];
  qp[t * 4 + 2] = qa[2];
  qp[t * 4 + 3] = qa[3];
  __syncthreads();
  if (t < 128) {
    float a = 0.f;
#pragma unroll
    for (int o = 0; o < 8; ++o) a += qp[((((t >> 2) << 3) + o) << 2) + (t & 3)];
    qpart[(size_t)slab * 2048 + chalf * 1024 + nw * 128 + t] = a;
  }
}

// ---------------- attn1: softmax + partial y over an n-eighth ---------------
__global__ __launch_bounds__(256) void k_attn1(
    const float* __restrict__ qpart, const u16* __restrict__ xbT,
    float* __restrict__ ypart) {
  __shared__ float red[4];
  __shared__ float sm[128];
  __shared__ float yp[4][512];
  const int slab = blockIdx.x >> 3, n8 = blockIdx.x & 7;
  const int t = threadIdx.x, w = t >> 6, l = t & 63;
  const float* q0 = qpart + (size_t)slab * 2048;
  const float* q1 = q0 + 1024;

  float4 qa = ((const float4*)q0)[t];
  float4 qb = ((const float4*)q1)[t];
  float4 q4 = make_float4(qa.x + qb.x, qa.y + qb.y, qa.z + qb.z, qa.w + qb.w);
  float m = fmaxf(fmaxf(q4.x, q4.y), fmaxf(q4.z, q4.w));
#pragma unroll
  for (int sh = 32; sh; sh >>= 1) m = fmaxf(m, __shfl_xor(m, sh, 64));
  if (l == 0) red[w] = m;
  __syncthreads();
  float gm = fmaxf(fmaxf(red[0], red[1]), fmaxf(red[2], red[3]));
  float s = __expf(q4.x - gm) + __expf(q4.y - gm) + __expf(q4.z - gm) + __expf(q4.w - gm);
#pragma unroll
  for (int sh = 32; sh; sh >>= 1) s += __shfl_xor(s, sh, 64);
  __syncthreads();
  if (l == 0) red[w] = s;
  __syncthreads();
  float gs = red[0] + red[1] + red[2] + red[3];
  if (t < 128) {
    const int n = n8 * 128 + t;
    sm[t] = __expf(q0[n] + q1[n] - gm) / gs;
  }
  __syncthreads();

  float ya[8] = {0.f, 0.f, 0.f, 0.f, 0.f, 0.f, 0.f, 0.f};
  const u16* xs = xbT + (size_t)slab * (NLEN * EMBED) + (size_t)(n8 * 128) * EMBED;
  for (int ni = 0; ni < 32; ++ni) {
    const int nloc = ni * 4 + w;
    const float sc = sm[nloc];
    u16x8 v = *(const u16x8*)(xs + (size_t)nloc * EMBED + l * 8);
#pragma unroll
    for (int j = 0; j < 8; ++j) ya[j] += sc * bf2f(v[j]);
  }
#pragma unroll
  for (int j = 0; j < 8; ++j) yp[w][l * 8 + j] = ya[j];
  __syncthreads();
  for (int c = t; c < 512; c += 256)
    ypart[((size_t)slab * 8 + n8) * 512 + c] = yp[0][c] + yp[1][c] + yp[2][c] + yp[3][c];
}

// ---------------- attn2: cv[e] = Wk[e]·y + bk[e] ----------------------------
__global__ __launch_bounds__(256) void k_attn2(
    const float* __restrict__ ypart, const float* __restrict__ Wqkv,
    const float* __restrict__ bqkv, float* __restrict__ cv) {
  __shared__ float yl[512];
  const int slab = blockIdx.x >> 2, ec = blockIdx.x & 3;
  const int t = threadIdx.x;
  const int e = ec * 256 + t;
  const float* yb = ypart + (size_t)slab * 8 * 512;
  for (int c = t; c < 512; c += 256) {
    float a = 0.f;
#pragma unroll
    for (int k = 0; k < 8; ++k) a += yb[k * 512 + c];
    yl[c] = a;
  }
  __syncthreads();
  const float* wk = Wqkv + (size_t)(1 + e) * EMBED;
  float a = 0.f;
#pragma unroll 4
  for (int c0 = 0; c0 < EMBED; c0 += 4) {
    float4 wv = *(const float4*)(wk + c0);
    a += wv.x * yl[c0] + wv.y * yl[c0 + 1] + wv.z * yl[c0 + 2] + wv.w * yl[c0 + 3];
  }
  cv[(size_t)slab * EXPAND + e] = a + bqkv[1 + e];
}

// ---------------- 128x128 GEMM core (m97 structure, BK=64, 32 KB LDS) -------
// D[128(m),128(n)] = A(128,K)*B(128,K)^T, k-contiguous rows, stride K.
// 256 thr = 4 waves (2m x 2n); per wave 64x64 out = acc[4][4].
// LDS 32 KB single-buffered (A 16K | B 16K), 16B-chunk swizzle ch^(row&7).
// Plain 2-barrier loop: stage -> sync -> 16 ds_read_b128 + 32 MFMA -> sync.
// Win mechanism = cross-block overlap (m114). Register math: 60 VGPR +
// 64 AGPR = 124 (accum_offset 64 -> 128 total) => 4 waves/EU fits EXACTLY
// (128*4=512); 5 forced a spill (r15: VGPR 48, WRITE +29MB, MfmaUtil 17%).
template <int K, int NT>
__device__ __forceinline__ void gemm128(const u16* __restrict__ Abase,
                                        const u16* __restrict__ Bbase,
                                        u16* lds, f32x4 (&acc)[4][4]) {
  const int t = threadIdx.x;
  const int w = t >> 6, l = t & 63;
  const int wr = w >> 1, wc = w & 1;
  const int lr = l & 15, lj = l >> 4;

#pragma unroll 1
  for (int kt = 0; kt < NT; ++kt) {
    const int kc0 = kt * 64;
#pragma unroll
    for (int i = 0; i < 4; ++i) {
      const int s = i * 256 + t;
      const int row = s >> 3, pch = s & 7;
      const int gch = (pch ^ (row & 7)) << 3;
      gld16(Abase + (size_t)row * K + kc0 + gch, lds + s * 8);
      gld16(Bbase + (size_t)row * K + kc0 + gch, lds + 8192 + s * 8);
    }
    __syncthreads();  // drains vmcnt -> staged data visible
    bf16x8 af[4][2], bg[4][2];
#pragma unroll
    for (int mi = 0; mi < 4; ++mi)
#pragma unroll
      for (int kc = 0; kc < 2; ++kc) {
        const int row = wr * 64 + mi * 16 + lr;
        af[mi][kc] = *(const bf16x8*)(lds + row * 64 +
                                      (((kc * 4 + lj) ^ (row & 7)) << 3));
      }
#pragma unroll
    for (int ni = 0; ni < 4; ++ni)
#pragma unroll
      for (int kc = 0; kc < 2; ++kc) {
        const int row = wc * 64 + ni * 16 + lr;
        bg[ni][kc] = *(const bf16x8*)(lds + 8192 + row * 64 +
                                      (((kc * 4 + lj) ^ (row & 7)) << 3));
      }
#pragma unroll
    for (int mi = 0; mi < 4; ++mi)
#pragma unroll
      for (int ni = 0; ni < 4; ++ni)
#pragma unroll
        for (int kc = 0; kc < 2; ++kc)
          acc[mi][ni] = MFMA(af[mi][kc], bg[ni][kc], acc[mi][ni]);
    __syncthreads();  // buffer reusable next iteration
  }
}

// ---------------- GEMM1: midT[n][e] = relu(valT + bv)*cv, bf16 --------------
// grid 4096 = 64 slabs x 8 tn x 8 te; te-siblings at bid stride 8 (same XCD).
__global__ __launch_bounds__(256, 4) void k_gemm1(
    const u16* __restrict__ xbT, const u16* __restrict__ WvB,
    const float* __restrict__ bqkv, const float* __restrict__ cv,
    u16* __restrict__ midT) {
  __shared__ __align__(16) u16 lds[16384];  // 32 KB
  const int bid = blockIdx.x;
  const int xc = bid & 7, k = bid >> 3;
  const int te = k & 7;
  const int gg = ((k >> 3) << 3) | xc;  // 0..511
  const int slab = gg >> 3, tn = gg & 7;
  const u16* A = xbT + (size_t)slab * (NLEN * EMBED) + (size_t)tn * 128 * EMBED;
  const u16* B = WvB + (size_t)te * 128 * EMBED;
  f32x4 acc[4][4];
  const f32x4 z = {0.f, 0.f, 0.f, 0.f};
#pragma unroll
  for (int i = 0; i < 4; ++i)
#pragma unroll
    for (int j = 0; j < 4; ++j) acc[i][j] = z;
  gemm128<EMBED, 8>(A, B, lds, acc);
  // loop tail: final __syncthreads -> LDS reusable for the C-tile (32 KB).

  const int t = threadIdx.x, w = t >> 6, l = t & 63;
  const int wr = w >> 1, wc = w & 1;
  const int lr = l & 15, lq4 = (l >> 4) * 4;
  // C tile 128n x 128e bf16 into LDS, chunk swizzle ch^(row&7) (16 chunks/row)
#pragma unroll
  for (int ni = 0; ni < 4; ++ni) {
    const int col = wc * 64 + ni * 16 + lr;
    const int e = te * 128 + col;
    const float bv = bqkv[1 + EXPAND + e];
    const float cve = cv[(size_t)slab * EXPAND + e];
#pragma unroll
    for (int mi = 0; mi < 4; ++mi) {
      const int nr = wr * 64 + mi * 16 + lq4;
#pragma unroll
      for (int r = 0; r < 4; ++r) {
        float v = acc[mi][ni][r] + bv;
        v = v > 0.f ? v * cve : 0.f;
        const int row = nr + r;
        lds[row * 128 + ((((col >> 3) ^ (row & 7)) << 3) | (col & 7))] = f2bf(v);
      }
    }
  }
  __syncthreads();
  // wide stores: wave w owns rows w*32..w*32+31; 4 rows x 16 chunks per iter
  u16* mt = midT + (size_t)slab * (NLEN * EXPAND) + (size_t)te * 128;
#pragma unroll
  for (int it = 0; it < 8; ++it) {
    const int row = w * 32 + it * 4 + (l >> 4);
    const int ch = (l & 15) ^ (row & 7);
    uint4 v = *(const uint4*)(lds + row * 128 + ch * 8);
    *(uint4*)(mt + (size_t)(tn * 128 + row) * EXPAND + (l & 15) * 8) = v;
  }
}

// ---------------- GEMM2: out = Wout*mid + bout ------------------------------
// grid 2048 = 64 slabs x 8 tn x 4 to; to-siblings at bid stride 8 (same XCD).
__global__ __launch_bounds__(256, 4) void k_gemm2(
    const u16* __restrict__ midT, const u16* __restrict__ WoutB,
    const float* __restrict__ bout, float* __restrict__ out) {
  __shared__ __align__(16) u16 lds[16384];  // 32 KB
  const int bid = blockIdx.x;
  const int xc = bid & 7, k = bid >> 3;
  const int to = k & 3;
  const int gg = ((k >> 2) << 3) | xc;  // 0..511
  const int slab = gg >> 3, tn = gg & 7;
  const int b = slab >> 4, p = slab & 15;
  const u16* A = midT + (size_t)slab * (NLEN * EXPAND) + (size_t)tn * 128 * EXPAND;
  const u16* B = WoutB + (size_t)to * 128 * EXPAND;
  f32x4 acc[4][4];
  const f32x4 z = {0.f, 0.f, 0.f, 0.f};
#pragma unroll
  for (int i = 0; i < 4; ++i)
#pragma unroll
    for (int j = 0; j < 4; ++j) acc[i][j] = z;
  gemm128<EXPAND, 16>(A, B, lds, acc);

  const int t = threadIdx.x, w = t >> 6, l = t & 63;
  const int wr = w >> 1, wc = w & 1;
  const int lr = l & 15, lq4 = (l >> 4) * 4;
  float* ob = out + (size_t)b * (EMBED * CHW) + (size_t)p * NLEN;
#pragma unroll
  for (int ni = 0; ni < 4; ++ni) {
    const int o = to * 128 + wc * 64 + ni * 16 + lr;
    const float bo = bout[o];
#pragma unroll
    for (int mi = 0; mi < 4; ++mi) {
      const int nr = tn * 128 + wr * 64 + mi * 16 + lq4;
      float4 v;
      v.x = acc[mi][ni][0] + bo;
      v.y = acc[mi][ni][1] + bo;
      v.z = acc[mi][ni][2] + bo;
      v.w = acc[mi][ni][3] + bo;
      *(float4*)(ob + (size_t)o * CHW + nr) = v;
    }
  }
}

extern "C" void kernel_launch(void* const* d_in, const int* in_sizes, int n_in,
                              void* d_out, int out_size, void* d_ws, size_t ws_size,
                              hipStream_t stream) {
  const float* x = (const float*)d_in[0];
  const float* Wqkv = (const float*)d_in[1];
  const float* bqkv = (const float*)d_in[2];
  const float* Wout = (const float*)d_in[3];
  const float* bout = (const float*)d_in[4];
  float* out = (float*)d_out;

  char* ws = (char*)d_ws;
  u16* xbT = (u16*)ws;                  // 67108864 B
  u16* WvB = (u16*)(ws + 67108864);     // 1048576 B
  u16* WoutB = (u16*)(ws + 68157440);   // 1048576 B
  float* cv = (float*)(ws + 69468160);  // 262144 B
  u16* midT = (u16*)(ws + 69730304);    // 134217728 B
  // overlays on midT's head (all consumed before gemm1 writes midT):
  float* ypart = (float*)(ws + 69730304);             // 64*8*512*4 = 1 MB
  float* qpart = (float*)(ws + 69730304 + 1048576);   // 64*2*1024*4 = 512 KB

  k_convert_w<<<1024, 256, 0, stream>>>(Wqkv, Wout, WvB, WoutB);
  k_convert_x<<<1024, 256, 0, stream>>>(x, Wqkv, qpart, xbT);
  k_attn1<<<512, 256, 0, stream>>>(qpart, xbT, ypart);
  k_attn2<<<256, 256, 0, stream>>>(ypart, Wqkv, bqkv, cv);
  k_gemm1<<<4096, 256, 0, stream>>>(xbT, WvB, bqkv, cv, midT);
  k_gemm2<<<2048, 256, 0, stream>>>(midT, WoutB, bout, out);
}

// Round 17
// 252.759 us; speedup vs baseline: 1.4162x; 1.0311x over previous
//
#include <hip/hip_runtime.h>

#define EMBED 512
#define EXPAND 1024
#define PNUM 16
#define NLEN 1024
#define CHW (PNUM * NLEN)  // 16384
#define SLABS 64

typedef unsigned short u16;
typedef unsigned int u32;
typedef __bf16 bf16x8 __attribute__((ext_vector_type(8)));
typedef u16 u16x8 __attribute__((ext_vector_type(8)));
typedef float f32x4 __attribute__((ext_vector_type(4)));

__device__ __forceinline__ u16 f2bf(float f) {
  u32 u = __builtin_bit_cast(u32, f);
  return (u16)((u + 0x7FFFu + ((u >> 16) & 1u)) >> 16);
}
__device__ __forceinline__ float bf2f(u16 h) {
  return __builtin_bit_cast(float, (u32)h << 16);
}
__device__ __forceinline__ void gld16(const u16* g, u16* l) {
  __builtin_amdgcn_global_load_lds((__attribute__((address_space(1))) void*)g,
                                   (__attribute__((address_space(3))) void*)l,
                                   16, 0, 0);
}
__device__ __forceinline__ f32x4 MFMA(bf16x8 a, bf16x8 b, f32x4 c) {
  return __builtin_amdgcn_mfma_f32_16x16x32_bf16(a, b, c, 0, 0, 0);
}

// ---------------- Kernel A: x->bf16 transpose + q partials, AND w-convert ----
// Grid 2048: bid<1024 = x path (slab x nw x chalf); bid>=1024 = weight path.
// Merging removes one serialized dispatch; the 3us of weight work fills CUs.
__global__ __launch_bounds__(256) void k_convert_xw(
    const float* __restrict__ x, const float* __restrict__ Wqkv,
    const float* __restrict__ Wout, float* __restrict__ qpart,
    u16* __restrict__ xbT, u16* __restrict__ WvB, u16* __restrict__ WoutB) {
  __shared__ __align__(16) u16 tile[128 * 64];  // 16 KB
  __shared__ float qp[256 * 4];                 // 4 KB
  const int t = threadIdx.x;
  if (blockIdx.x >= 1024) {
    // ---- weight conversion path (former k_convert_w)
    const int NV = EXPAND * EMBED;  // 524288
    int idx = ((blockIdx.x - 1024) * 256 + t) * 4;
    if (idx < NV) {
      float4 v = *(const float4*)(Wqkv + (size_t)(1 + EXPAND) * EMBED + idx);
      uint2 u = make_uint2((u32)f2bf(v.x) | ((u32)f2bf(v.y) << 16),
                           (u32)f2bf(v.z) | ((u32)f2bf(v.w) << 16));
      *(uint2*)(WvB + idx) = u;
    } else {
      int j = idx - NV;
      float4 v = *(const float4*)(Wout + j);
      uint2 u = make_uint2((u32)f2bf(v.x) | ((u32)f2bf(v.y) << 16),
                           (u32)f2bf(v.z) | ((u32)f2bf(v.w) << 16));
      *(uint2*)(WoutB + j) = u;
    }
    return;
  }
  // ---- x path
  const int slab = blockIdx.x >> 4;
  const int nw = (blockIdx.x >> 1) & 7;
  const int chalf = blockIdx.x & 1;
  const int b = slab >> 4, p = slab & 15;
  const int c8 = t & 7;
  const int ng = t >> 3;
  const float* xs = x + (size_t)b * (EMBED * CHW) + (size_t)p * NLEN + nw * 128;
  u16* dst = xbT + (size_t)slab * (NLEN * EMBED) + (size_t)(nw * 128) * EMBED;
  float qa[4] = {0.f, 0.f, 0.f, 0.f};

  for (int cc = 0; cc < 4; ++cc) {
    const int cbase = chalf * 256 + cc * 64;
    float4 v[8];
#pragma unroll
    for (int k = 0; k < 8; ++k)
      v[k] = *(const float4*)(xs + (size_t)(cbase + c8 * 8 + k) * CHW + ng * 4);
    const float* w0 = Wqkv + cbase + c8 * 8;
#pragma unroll
    for (int k = 0; k < 8; ++k) {
      qa[0] += w0[k] * v[k].x;
      qa[1] += w0[k] * v[k].y;
      qa[2] += w0[k] * v[k].z;
      qa[3] += w0[k] * v[k].w;
    }
#pragma unroll
    for (int j = 0; j < 4; ++j) {
      const int nl = ng * 4 + j;
      float e[8];
#pragma unroll
      for (int k = 0; k < 8; ++k)
        e[k] = (j == 0) ? v[k].x : (j == 1) ? v[k].y : (j == 2) ? v[k].z : v[k].w;
      uint4 pk;
      pk.x = (u32)f2bf(e[0]) | ((u32)f2bf(e[1]) << 16);
      pk.y = (u32)f2bf(e[2]) | ((u32)f2bf(e[3]) << 16);
      pk.z = (u32)f2bf(e[4]) | ((u32)f2bf(e[5]) << 16);
      pk.w = (u32)f2bf(e[6]) | ((u32)f2bf(e[7]) << 16);
      *(uint4*)(tile + nl * 64 + ((c8 ^ (nl & 7)) << 3)) = pk;
    }
    __syncthreads();
#pragma unroll
    for (int m = 0; m < 4; ++m) {
      const int s = m * 256 + t;
      const int nl = s >> 3, ch = s & 7;
      uint4 vv = *(const uint4*)(tile + nl * 64 + ((ch ^ (nl & 7)) << 3));
      *(uint4*)(dst + (size_t)nl * EMBED + cbase + ch * 8) = vv;
    }
    __syncthreads();
  }
  qp[t * 4 + 0] = qa[0];
  qp[t * 4 + 1] = qa[1];
  qp[t * 4 + 2] = qa[2];
  qp[t * 4 + 3] = qa[3];
  __syncthreads();
  if (t < 128) {
    float a = 0.f;
#pragma unroll
    for (int o = 0; o < 8; ++o) a += qp[((((t >> 2) << 3) + o) << 2) + (t & 3)];
    qpart[(size_t)slab * 2048 + chalf * 1024 + nw * 128 + t] = a;
  }
}

// ---------------- attn1: softmax + partial y over an n-eighth ---------------
__global__ __launch_bounds__(256) void k_attn1(
    const float* __restrict__ qpart, const u16* __restrict__ xbT,
    float* __restrict__ ypart) {
  __shared__ float red[4];
  __shared__ float sm[128];
  __shared__ float yp[4][512];
  const int slab = blockIdx.x >> 3, n8 = blockIdx.x & 7;
  const int t = threadIdx.x, w = t >> 6, l = t & 63;
  const float* q0 = qpart + (size_t)slab * 2048;
  const float* q1 = q0 + 1024;

  float4 qa = ((const float4*)q0)[t];
  float4 qb = ((const float4*)q1)[t];
  float4 q4 = make_float4(qa.x + qb.x, qa.y + qb.y, qa.z + qb.z, qa.w + qb.w);
  float m = fmaxf(fmaxf(q4.x, q4.y), fmaxf(q4.z, q4.w));
#pragma unroll
  for (int sh = 32; sh; sh >>= 1) m = fmaxf(m, __shfl_xor(m, sh, 64));
  if (l == 0) red[w] = m;
  __syncthreads();
  float gm = fmaxf(fmaxf(red[0], red[1]), fmaxf(red[2], red[3]));
  float s = __expf(q4.x - gm) + __expf(q4.y - gm) + __expf(q4.z - gm) + __expf(q4.w - gm);
#pragma unroll
  for (int sh = 32; sh; sh >>= 1) s += __shfl_xor(s, sh, 64);
  __syncthreads();
  if (l == 0) red[w] = s;
  __syncthreads();
  float gs = red[0] + red[1] + red[2] + red[3];
  if (t < 128) {
    const int n = n8 * 128 + t;
    sm[t] = __expf(q0[n] + q1[n] - gm) / gs;
  }
  __syncthreads();

  float ya[8] = {0.f, 0.f, 0.f, 0.f, 0.f, 0.f, 0.f, 0.f};
  const u16* xs = xbT + (size_t)slab * (NLEN * EMBED) + (size_t)(n8 * 128) * EMBED;
  for (int ni = 0; ni < 32; ++ni) {
    const int nloc = ni * 4 + w;
    const float sc = sm[nloc];
    u16x8 v = *(const u16x8*)(xs + (size_t)nloc * EMBED + l * 8);
#pragma unroll
    for (int j = 0; j < 8; ++j) ya[j] += sc * bf2f(v[j]);
  }
#pragma unroll
  for (int j = 0; j < 8; ++j) yp[w][l * 8 + j] = ya[j];
  __syncthreads();
  for (int c = t; c < 512; c += 256)
    ypart[((size_t)slab * 8 + n8) * 512 + c] = yp[0][c] + yp[1][c] + yp[2][c] + yp[3][c];
}

// ---------------- attn2: cv[e] = Wk[e]·y + bk[e] ----------------------------
__global__ __launch_bounds__(256) void k_attn2(
    const float* __restrict__ ypart, const float* __restrict__ Wqkv,
    const float* __restrict__ bqkv, float* __restrict__ cv) {
  __shared__ float yl[512];
  const int slab = blockIdx.x >> 2, ec = blockIdx.x & 3;
  const int t = threadIdx.x;
  const int e = ec * 256 + t;
  const float* yb = ypart + (size_t)slab * 8 * 512;
  for (int c = t; c < 512; c += 256) {
    float a = 0.f;
#pragma unroll
    for (int k = 0; k < 8; ++k) a += yb[k * 512 + c];
    yl[c] = a;
  }
  __syncthreads();
  const float* wk = Wqkv + (size_t)(1 + e) * EMBED;
  float a = 0.f;
#pragma unroll 4
  for (int c0 = 0; c0 < EMBED; c0 += 4) {
    float4 wv = *(const float4*)(wk + c0);
    a += wv.x * yl[c0] + wv.y * yl[c0 + 1] + wv.z * yl[c0 + 2] + wv.w * yl[c0 + 3];
  }
  cv[(size_t)slab * EXPAND + e] = a + bqkv[1 + e];
}

// ---------------- 128x128 GEMM core (m97 structure, BK=64, 32 KB LDS) -------
// Unchanged r16 winner; see comments there.
template <int K, int NT>
__device__ __forceinline__ void gemm128(const u16* __restrict__ Abase,
                                        const u16* __restrict__ Bbase,
                                        u16* lds, f32x4 (&acc)[4][4]) {
  const int t = threadIdx.x;
  const int w = t >> 6, l = t & 63;
  const int wr = w >> 1, wc = w & 1;
  const int lr = l & 15, lj = l >> 4;

#pragma unroll 1
  for (int kt = 0; kt < NT; ++kt) {
    const int kc0 = kt * 64;
#pragma unroll
    for (int i = 0; i < 4; ++i) {
      const int s = i * 256 + t;
      const int row = s >> 3, pch = s & 7;
      const int gch = (pch ^ (row & 7)) << 3;
      gld16(Abase + (size_t)row * K + kc0 + gch, lds + s * 8);
      gld16(Bbase + (size_t)row * K + kc0 + gch, lds + 8192 + s * 8);
    }
    __syncthreads();
    bf16x8 af[4][2], bg[4][2];
#pragma unroll
    for (int mi = 0; mi < 4; ++mi)
#pragma unroll
      for (int kc = 0; kc < 2; ++kc) {
        const int row = wr * 64 + mi * 16 + lr;
        af[mi][kc] = *(const bf16x8*)(lds + row * 64 +
                                      (((kc * 4 + lj) ^ (row & 7)) << 3));
      }
#pragma unroll
    for (int ni = 0; ni < 4; ++ni)
#pragma unroll
      for (int kc = 0; kc < 2; ++kc) {
        const int row = wc * 64 + ni * 16 + lr;
        bg[ni][kc] = *(const bf16x8*)(lds + 8192 + row * 64 +
                                      (((kc * 4 + lj) ^ (row & 7)) << 3));
      }
#pragma unroll
    for (int mi = 0; mi < 4; ++mi)
#pragma unroll
      for (int ni = 0; ni < 4; ++ni)
#pragma unroll
        for (int kc = 0; kc < 2; ++kc)
          acc[mi][ni] = MFMA(af[mi][kc], bg[ni][kc], acc[mi][ni]);
    __syncthreads();
  }
}

// ---------------- GEMM1: midT[n][e] = relu(valT + bv)*cv, bf16 (r16) --------
__global__ __launch_bounds__(256, 4) void k_gemm1(
    const u16* __restrict__ xbT, const u16* __restrict__ WvB,
    const float* __restrict__ bqkv, const float* __restrict__ cv,
    u16* __restrict__ midT) {
  __shared__ __align__(16) u16 lds[16384];  // 32 KB
  const int bid = blockIdx.x;
  const int xc = bid & 7, k = bid >> 3;
  const int te = k & 7;
  const int gg = ((k >> 3) << 3) | xc;  // 0..511
  const int slab = gg >> 3, tn = gg & 7;
  const u16* A = xbT + (size_t)slab * (NLEN * EMBED) + (size_t)tn * 128 * EMBED;
  const u16* B = WvB + (size_t)te * 128 * EMBED;
  f32x4 acc[4][4];
  const f32x4 z = {0.f, 0.f, 0.f, 0.f};
#pragma unroll
  for (int i = 0; i < 4; ++i)
#pragma unroll
    for (int j = 0; j < 4; ++j) acc[i][j] = z;
  gemm128<EMBED, 8>(A, B, lds, acc);

  const int t = threadIdx.x, w = t >> 6, l = t & 63;
  const int wr = w >> 1, wc = w & 1;
  const int lr = l & 15, lq4 = (l >> 4) * 4;
#pragma unroll
  for (int ni = 0; ni < 4; ++ni) {
    const int col = wc * 64 + ni * 16 + lr;
    const int e = te * 128 + col;
    const float bv = bqkv[1 + EXPAND + e];
    const float cve = cv[(size_t)slab * EXPAND + e];
#pragma unroll
    for (int mi = 0; mi < 4; ++mi) {
      const int nr = wr * 64 + mi * 16 + lq4;
#pragma unroll
      for (int r = 0; r < 4; ++r) {
        float v = acc[mi][ni][r] + bv;
        v = v > 0.f ? v * cve : 0.f;
        const int row = nr + r;
        lds[row * 128 + ((((col >> 3) ^ (row & 7)) << 3) | (col & 7))] = f2bf(v);
      }
    }
  }
  __syncthreads();
  u16* mt = midT + (size_t)slab * (NLEN * EXPAND) + (size_t)te * 128;
#pragma unroll
  for (int it = 0; it < 8; ++it) {
    const int row = w * 32 + it * 4 + (l >> 4);
    const int ch = (l & 15) ^ (row & 7);
    uint4 v = *(const uint4*)(lds + row * 128 + ch * 8);
    *(uint4*)(mt + (size_t)(tn * 128 + row) * EXPAND + (l & 15) * 8) = v;
  }
}

// ---------------- GEMM2: 256n x 128o tile, 8 waves, 2 blocks/CU -------------
// out[o][n] = sum_e WoutB[o][e] * midT[n][e] + bout[o].
// A = midT (256 n-rows), B = WoutB (128 o-rows), BK=64, LDS 48 KB.
// 8 waves = 4 n-quarters x 2 o-halves; per-wave 64x64 out (acc=64 regs ->
// same 124-reg footprint as the 128^2 winner => (512,4) = 2 blocks/CU =
// 16 waves/CU, vs ~9.6 measured on r16's gemm2. Same 16:32 read:MFMA ratio.
// grid 1024 = 64 slabs x 4 tn x 4 to; to-siblings at bid stride 8 (same XCD,
// share the midT A-panel in L2).
__global__ __launch_bounds__(512, 4) void k_gemm2(
    const u16* __restrict__ midT, const u16* __restrict__ WoutB,
    const float* __restrict__ bout, float* __restrict__ out) {
  __shared__ __align__(16) u16 lds[24576];  // 48 KB: A 32K | B 16K
  const int bid = blockIdx.x;
  const int xc = bid & 7, k = bid >> 3;
  const int to = k & 3;
  const int gg = ((k >> 2) << 3) | xc;  // 0..255
  const int slab = gg >> 2, tn = gg & 3;
  const int b = slab >> 4, p = slab & 15;
  const u16* A = midT + (size_t)slab * (NLEN * EXPAND) + (size_t)tn * 256 * EXPAND;
  const u16* B = WoutB + (size_t)to * 128 * EXPAND;
  const int t = threadIdx.x, w = t >> 6, l = t & 63;
  const int wr = w >> 1, wc = w & 1;  // wr: n-quarter 0..3, wc: o-half 0..1
  const int lr = l & 15, lj = l >> 4, lq4 = (l >> 4) * 4;
  f32x4 acc[4][4];
  const f32x4 z = {0.f, 0.f, 0.f, 0.f};
#pragma unroll
  for (int i = 0; i < 4; ++i)
#pragma unroll
    for (int j = 0; j < 4; ++j) acc[i][j] = z;

#pragma unroll 1
  for (int kt = 0; kt < 16; ++kt) {
    const int kc0 = kt * 64;
    // stage A (256 rows x 64 k = 2048 chunks, 4/thread)
#pragma unroll
    for (int i = 0; i < 4; ++i) {
      const int s = i * 512 + t;
      const int row = s >> 3, pch = s & 7;
      gld16(A + (size_t)row * EXPAND + kc0 + ((pch ^ (row & 7)) << 3),
            lds + s * 8);
    }
    // stage B (128 rows x 64 k = 1024 chunks, 2/thread)
#pragma unroll
    for (int i = 0; i < 2; ++i) {
      const int s = i * 512 + t;
      const int row = s >> 3, pch = s & 7;
      gld16(B + (size_t)row * EXPAND + kc0 + ((pch ^ (row & 7)) << 3),
            lds + 16384 + s * 8);
    }
    __syncthreads();
    bf16x8 af[4][2], bg[4][2];
#pragma unroll
    for (int mi = 0; mi < 4; ++mi)
#pragma unroll
      for (int kc = 0; kc < 2; ++kc) {
        const int row = wr * 64 + mi * 16 + lr;  // n-rows
        af[mi][kc] = *(const bf16x8*)(lds + row * 64 +
                                      (((kc * 4 + lj) ^ (row & 7)) << 3));
      }
#pragma unroll
    for (int ni = 0; ni < 4; ++ni)
#pragma unroll
      for (int kc = 0; kc < 2; ++kc) {
        const int row = wc * 64 + ni * 16 + lr;  // o-rows
        bg[ni][kc] = *(const bf16x8*)(lds + 16384 + row * 64 +
                                      (((kc * 4 + lj) ^ (row & 7)) << 3));
      }
#pragma unroll
    for (int mi = 0; mi < 4; ++mi)
#pragma unroll
      for (int ni = 0; ni < 4; ++ni)
#pragma unroll
        for (int kc = 0; kc < 2; ++kc)
          acc[mi][ni] = MFMA(af[mi][kc], bg[ni][kc], acc[mi][ni]);
    __syncthreads();
  }

  // epilogue: D quad = 4 consecutive n at fixed o -> direct float4 stores
  float* ob = out + (size_t)b * (EMBED * CHW) + (size_t)p * NLEN;
#pragma unroll
  for (int ni = 0; ni < 4; ++ni) {
    const int o = to * 128 + wc * 64 + ni * 16 + lr;
    const float bo = bout[o];
#pragma unroll
    for (int mi = 0; mi < 4; ++mi) {
      const int nr = tn * 256 + wr * 64 + mi * 16 + lq4;
      float4 v;
      v.x = acc[mi][ni][0] + bo;
      v.y = acc[mi][ni][1] + bo;
      v.z = acc[mi][ni][2] + bo;
      v.w = acc[mi][ni][3] + bo;
      *(float4*)(ob + (size_t)o * CHW + nr) = v;
    }
  }
}

extern "C" void kernel_launch(void* const* d_in, const int* in_sizes, int n_in,
                              void* d_out, int out_size, void* d_ws, size_t ws_size,
                              hipStream_t stream) {
  const float* x = (const float*)d_in[0];
  const float* Wqkv = (const float*)d_in[1];
  const float* bqkv = (const float*)d_in[2];
  const float* Wout = (const float*)d_in[3];
  const float* bout = (const float*)d_in[4];
  float* out = (float*)d_out;

  char* ws = (char*)d_ws;
  u16* xbT = (u16*)ws;                  // 67108864 B
  u16* WvB = (u16*)(ws + 67108864);     // 1048576 B
  u16* WoutB = (u16*)(ws + 68157440);   // 1048576 B
  float* cv = (float*)(ws + 69468160);  // 262144 B
  u16* midT = (u16*)(ws + 69730304);    // 134217728 B
  // overlays on midT's head (all consumed before gemm1 writes midT):
  float* ypart = (float*)(ws + 69730304);             // 64*8*512*4 = 1 MB
  float* qpart = (float*)(ws + 69730304 + 1048576);   // 64*2*1024*4 = 512 KB

  k_convert_xw<<<2048, 256, 0, stream>>>(x, Wqkv, Wout, qpart, xbT, WvB, WoutB);
  k_attn1<<<512, 256, 0, stream>>>(qpart, xbT, ypart);
  k_attn2<<<256, 256, 0, stream>>>(ypart, Wqkv, bqkv, cv);
  k_gemm1<<<4096, 256, 0, stream>>>(xbT, WvB, bqkv, cv, midT);
  k_gemm2<<<1024, 512, 0, stream>>>(midT, WoutB, bout, out);
}